// Round 6
// baseline (247.863 us; speedup 1.0000x reference)
//
#include <hip/hip_runtime.h>
#include <hip/hip_bf16.h>

#define N_NODES 50000
#define N_EDGES 800000
#define IN_C 128
#define HC 128
#define HEADS 8
#define OUT_C 16
#define NEG_SLOPE 0.2f
#define LN_EPS 1e-5f
#define SCAN_BLOCKS 196         // ceil(50176/256)

#define MB 80                   // nodes per node_phase block (625*80 = 50000)
#define LDW 136                 // LDS row stride in bf16 elems (128 + 8 pad)

typedef __hip_bfloat16 bf16;
typedef __attribute__((ext_vector_type(8))) short short8;
typedef __attribute__((ext_vector_type(4))) float f32x4;

__device__ __forceinline__ float b2f(bf16 v) { return __bfloat162float(v); }

// float -> bf16 bits, round-to-nearest-even
__device__ __forceinline__ unsigned short f2bf(float f) {
    unsigned u = __float_as_uint(f);
    return (unsigned short)((u + 0x7fffu + ((u >> 16) & 1u)) >> 16);
}
__device__ __forceinline__ float bf2f(unsigned short s) {
    unsigned u = ((unsigned)s) << 16;
    return __uint_as_float(u);
}

// ---------------------------------------------------------------------------
// Stage 1 (MFMA): h = x @ W.  80 nodes/block, 4 waves; wave owns 32 cols:
// 5 M-tiles x 2 N-tiles of mfma_f32_16x16x32_bf16.  x,W staged bf16 in LDS
// (W transposed so B-frags are k-contiguous b128 reads).  Epilogue: h-tile
// through LDS -> vectorized global store + a_src/a_dst per (node,head) dots.
// Fused: per-dst degree count (625 blocks * 1280 = N_EDGES exactly).
// ---------------------------------------------------------------------------
__global__ __launch_bounds__(256) void node_phase(
    const float* __restrict__ x, const float* __restrict__ W,
    const float* __restrict__ att_src, const float* __restrict__ att_dst,
    const int* __restrict__ ei, int* __restrict__ deg,
    unsigned short* __restrict__ h_out,
    float* __restrict__ a_src, float* __restrict__ a_dst)
{
    __shared__ short sW[128 * LDW];   // Wt[n][k] bf16
    __shared__ short sX[MB * LDW];    // x-tile bf16; reused as h-tile in epilogue

    const int t  = threadIdx.x;       // 0..255
    const int wv = t >> 6;
    const int l  = t & 63;
    const int n0 = blockIdx.x * MB;

    // fused CSR degree count (exact cover: 625*1280 == 800000)
#pragma unroll
    for (int i = 0; i < 5; ++i) {
        int e = blockIdx.x * 1280 + i * 256 + t;
        atomicAdd(&deg[ei[N_EDGES + e]], 1);
    }

    // W (row-major [k][n]) -> LDS transposed bf16 Wt[n][k]
    {
        const int k  = t >> 1;
        const int nb = (t & 1) * 64;
#pragma unroll
        for (int i = 0; i < 16; ++i) {
            float4 w4 = *reinterpret_cast<const float4*>(W + k * HC + nb + i * 4);
            sW[(nb + i * 4 + 0) * LDW + k] = (short)f2bf(w4.x);
            sW[(nb + i * 4 + 1) * LDW + k] = (short)f2bf(w4.y);
            sW[(nb + i * 4 + 2) * LDW + k] = (short)f2bf(w4.z);
            sW[(nb + i * 4 + 3) * LDW + k] = (short)f2bf(w4.w);
        }
    }
    // x tile -> LDS bf16 (row-major, padded)
#pragma unroll
    for (int i = 0; i < 10; ++i) {
        int idx = i * 256 + t;            // 2560 float4 chunks
        int m   = idx >> 5;
        int c4  = idx & 31;
        float4 v = *reinterpret_cast<const float4*>(
            x + (size_t)(n0 + m) * IN_C + c4 * 4);
        ushort4 pk = make_ushort4(f2bf(v.x), f2bf(v.y), f2bf(v.z), f2bf(v.w));
        *reinterpret_cast<ushort4*>(sX + m * LDW + c4 * 4) = pk;
    }
    __syncthreads();

    // K loop: 4 steps of 32
    f32x4 acc[5][2];
#pragma unroll
    for (int mt = 0; mt < 5; ++mt) { acc[mt][0] = (f32x4)0.f; acc[mt][1] = (f32x4)0.f; }

    const int mrow = l & 15;
    const int kgrp = (l >> 4) * 8;
    const int nc0  = (wv * 32 + (l & 15)) * LDW;
    const int nc1  = (wv * 32 + 16 + (l & 15)) * LDW;

#pragma unroll
    for (int ko = 0; ko < IN_C; ko += 32) {
        short8 b0 = *reinterpret_cast<const short8*>(sW + nc0 + ko + kgrp);
        short8 b1 = *reinterpret_cast<const short8*>(sW + nc1 + ko + kgrp);
#pragma unroll
        for (int mt = 0; mt < 5; ++mt) {
            short8 a = *reinterpret_cast<const short8*>(
                sX + (mt * 16 + mrow) * LDW + ko + kgrp);
            acc[mt][0] = __builtin_amdgcn_mfma_f32_16x16x32_bf16(a, b0, acc[mt][0], 0, 0, 0);
            acc[mt][1] = __builtin_amdgcn_mfma_f32_16x16x32_bf16(a, b1, acc[mt][1], 0, 0, 0);
        }
    }
    __syncthreads();                       // all sX reads done

    // acc -> LDS h-tile (bf16), C/D layout: col = lane&15, row = (lane>>4)*4+reg
#pragma unroll
    for (int mt = 0; mt < 5; ++mt)
#pragma unroll
        for (int nt = 0; nt < 2; ++nt)
#pragma unroll
            for (int r = 0; r < 4; ++r) {
                int row = mt * 16 + (l >> 4) * 4 + r;
                int col = wv * 32 + nt * 16 + (l & 15);
                sX[row * LDW + col] = (short)f2bf(acc[mt][nt][r]);
            }
    __syncthreads();

    // h global store: 80 rows * 128 bf16 = 1280 x 16B chunks
#pragma unroll
    for (int i = 0; i < 5; ++i) {
        int idx = i * 256 + t;
        int m   = idx >> 4;
        int v8  = idx & 15;
        short8 hv = *reinterpret_cast<const short8*>(sX + m * LDW + v8 * 8);
        *reinterpret_cast<short8*>(h_out + (size_t)(n0 + m) * HC + v8 * 8) = hv;
    }

    // a_src/a_dst: 640 (node,head) pairs, 16-dot each
#pragma unroll
    for (int i = 0; i < 3; ++i) {
        int p = i * 256 + t;
        if (p < MB * HEADS) {
            int m  = p >> 3;
            int hd = p & 7;
            float ssum = 0.f, dsum = 0.f;
#pragma unroll
            for (int c = 0; c < 16; ++c) {
                float hv = bf2f((unsigned short)sX[m * LDW + hd * 16 + c]);
                ssum = fmaf(hv, att_src[hd * 16 + c], ssum);
                dsum = fmaf(hv, att_dst[hd * 16 + c], dsum);
            }
            a_src[(n0 + m) * HEADS + hd] = ssum;
            a_dst[(n0 + m) * HEADS + hd] = dsum;
        }
    }
}

// ---------------------------------------------------------------------------
// Hierarchical scan, stage 1: per-block (256-elem) exclusive scan.
// Writes local[], blocksum[], and RE-ZEROES deg so k_fill reuses it as cursor.
// ---------------------------------------------------------------------------
__global__ __launch_bounds__(256) void scan_local(
    int* __restrict__ deg, int* __restrict__ local, int* __restrict__ blocksum)
{
    __shared__ int wtot[4], wbase[4];
    const int t    = threadIdx.x;
    const int lane = t & 63;
    const int i    = blockIdx.x * 256 + t;
    const int d    = (i < N_NODES) ? deg[i] : 0;

    int inc = d;
#pragma unroll
    for (int off = 1; off < 64; off <<= 1) {
        int v = __shfl_up(inc, off, 64);
        if (lane >= off) inc += v;
    }
    if (lane == 63) wtot[t >> 6] = inc;
    __syncthreads();
    if (t == 0) {
        int r = 0;
#pragma unroll
        for (int w = 0; w < 4; ++w) { wbase[w] = r; r += wtot[w]; }
    }
    __syncthreads();

    local[i] = inc - d + wbase[t >> 6];
    if (t == 255) blocksum[blockIdx.x] = wbase[3] + wtot[3];
    if (i < N_NODES) deg[i] = 0;              // becomes k_fill's cursor
}

__global__ __launch_bounds__(256) void scan_base(
    const int* __restrict__ blocksum, int* __restrict__ base)
{
    __shared__ int wtot[4], wbase[4];
    const int t    = threadIdx.x;
    const int lane = t & 63;
    const int d    = (t < SCAN_BLOCKS) ? blocksum[t] : 0;

    int inc = d;
#pragma unroll
    for (int off = 1; off < 64; off <<= 1) {
        int v = __shfl_up(inc, off, 64);
        if (lane >= off) inc += v;
    }
    if (lane == 63) wtot[t >> 6] = inc;
    __syncthreads();
    if (t == 0) {
        int r = 0;
#pragma unroll
        for (int w = 0; w < 4; ++w) { wbase[w] = r; r += wtot[w]; }
    }
    __syncthreads();
    if (t < SCAN_BLOCKS) base[t] = inc - d + wbase[t >> 6];
}

// ---------------------------------------------------------------------------
// CSR fill. offs(i) = local[i] + base[i>>8]; deg (re-zeroed) is the cursor.
// ---------------------------------------------------------------------------
__global__ __launch_bounds__(256) void k_fill(
    const int* __restrict__ ei, const float* __restrict__ edge_attr,
    const int* __restrict__ local, const int* __restrict__ base,
    int* __restrict__ deg, int2* __restrict__ csr)
{
    int e = blockIdx.x * 256 + threadIdx.x;
    if (e >= N_EDGES) return;
    int d = ei[N_EDGES + e];
    int pos = atomicAdd(&deg[d], 1);
    int slot = local[d] + base[d >> 8] + pos;
    csr[slot] = make_int2(ei[e], __float_as_int(edge_attr[e]));
}

// ---------------------------------------------------------------------------
// Fused gather: single-pass softmax (normalize at end), wave-parallel logits
// (8 edges x 8 heads per chunk), coalesced 256B h-row FMAs, fused epilogue.
// ---------------------------------------------------------------------------
__global__ __launch_bounds__(256) void gather_node(
    const int* __restrict__ local, const int* __restrict__ base,
    const int2* __restrict__ csr,
    const float* __restrict__ a_src, const float* __restrict__ a_dst,
    const bf16* __restrict__ h,
    const float* __restrict__ x, const float* __restrict__ bvec,
    const float* __restrict__ gamma, const float* __restrict__ beta,
    const float* __restrict__ att_edge, const float* __restrict__ lin_w,
    const float* __restrict__ lin_b,
    float* __restrict__ out)
{
    const int wave = threadIdx.x >> 6;
    const int l    = threadIdx.x & 63;
    const int n    = blockIdx.x * 4 + wave;       // 50000 % 4 == 0
    const int hh   = l >> 3;
    const int jj   = l & 7;

    float ae0 = att_edge[2 * l], ae1 = att_edge[2 * l + 1];
    float p = ae0 * lin_w[2 * l] + ae1 * lin_w[2 * l + 1];
    float q = ae0 * lin_b[2 * l] + ae1 * lin_b[2 * l + 1];
#pragma unroll
    for (int off = 1; off <= 4; off <<= 1) {
        p += __shfl_xor(p, off, 64);
        q += __shfl_xor(q, off, 64);
    }

    const float ad  = a_dst[n * HEADS + hh];
    const int   beg = local[n]     + base[n >> 8];
    const int   end = local[n + 1] + base[(n + 1) >> 8];

    float z = 0.f, acc0 = 0.f, acc1 = 0.f;
    const __hip_bfloat162* h2 = reinterpret_cast<const __hip_bfloat162*>(h);

    for (int bs = beg; bs < end; bs += 8) {
        const int  slot = bs + jj;
        const bool v    = slot < end;
        int  sl = 0; float ev = 0.f;
        if (v) {
            int2 ce = csr[slot];
            sl = ce.x;
            float ea = __int_as_float(ce.y);
            float lg = a_src[sl * HEADS + hh] + ad + ea * p + q;
            lg = lg > 0.f ? lg : NEG_SLOPE * lg;
            ev = __expf(lg);
        }
        float zs = ev;
        zs += __shfl_xor(zs, 1, 64);
        zs += __shfl_xor(zs, 2, 64);
        zs += __shfl_xor(zs, 4, 64);
        z += zs;

        const int cnt = min(8, end - bs);
        const int gbase = l & 56;
        if (cnt == 8) {
#pragma unroll
            for (int j = 0; j < 8; ++j) {
                float evj = __shfl(ev, gbase | j, 64);
                int   sj  = __shfl(sl, gbase | j, 64);
                __hip_bfloat162 hv = h2[(size_t)sj * 64 + l];
                acc0 += evj * b2f(hv.x);
                acc1 += evj * b2f(hv.y);
            }
        } else {
            for (int j = 0; j < cnt; ++j) {
                float evj = __shfl(ev, gbase | j, 64);
                int   sj  = __shfl(sl, gbase | j, 64);
                __hip_bfloat162 hv = h2[(size_t)sj * 64 + l];
                acc0 += evj * b2f(hv.x);
                acc1 += evj * b2f(hv.y);
            }
        }
    }
    const float rz = 1.f / (z + 1e-16f);
    acc0 *= rz;
    acc1 *= rz;

    const size_t idx = (size_t)n * HC + 2 * l;
    const float2 xv = *reinterpret_cast<const float2*>(x + idx);
    const float2 bv = *reinterpret_cast<const float2*>(bvec + 2 * l);
    float v0 = acc0 + xv.x + bv.x;
    float v1 = acc1 + xv.y + bv.y;
    float s1 = v0 + v1, s2 = v0 * v0 + v1 * v1;
#pragma unroll
    for (int off = 32; off >= 1; off >>= 1) {
        s1 += __shfl_xor(s1, off, 64);
        s2 += __shfl_xor(s2, off, 64);
    }
    const float mean = s1 * (1.f / HC);
    const float var  = s2 * (1.f / HC) - mean * mean;
    const float inv  = rsqrtf(var + LN_EPS);
    const float2 gv = *reinterpret_cast<const float2*>(gamma + 2 * l);
    const float2 be = *reinterpret_cast<const float2*>(beta + 2 * l);
    float y0 = (v0 - mean) * inv * gv.x + be.x;
    float y1 = (v1 - mean) * inv * gv.y + be.y;
    y0 = y0 > 0.f ? y0 : expm1f(y0);
    y1 = y1 > 0.f ? y1 : expm1f(y1);
    *reinterpret_cast<float2*>(out + idx) = make_float2(y0, y1);
}

// ---------------------------------------------------------------------------
extern "C" void kernel_launch(void* const* d_in, const int* in_sizes, int n_in,
                              void* d_out, int out_size, void* d_ws, size_t ws_size,
                              hipStream_t stream)
{
    const float* x         = (const float*)d_in[0];
    const int*   ei        = (const int*)d_in[1];
    const float* edge_attr = (const float*)d_in[2];
    const float* W         = (const float*)d_in[3];
    const float* b         = (const float*)d_in[4];
    const float* att_src   = (const float*)d_in[5];
    const float* att_dst   = (const float*)d_in[6];
    const float* att_edge  = (const float*)d_in[7];
    const float* lin_w     = (const float*)d_in[8];
    const float* lin_b     = (const float*)d_in[9];
    const float* gamma     = (const float*)d_in[10];
    const float* beta      = (const float*)d_in[11];

    char* ws = (char*)d_ws;
    bf16*  h        = (bf16*)ws; ws += (size_t)N_NODES * HC * sizeof(bf16);      // 12.8 MB
    float* a_src    = (float*)ws; ws += (size_t)N_NODES * HEADS * sizeof(float); //  1.6 MB
    float* a_dst    = (float*)ws; ws += (size_t)N_NODES * HEADS * sizeof(float); //  1.6 MB
    int*   deg      = (int*)ws;   ws += (size_t)N_NODES * sizeof(int);           //  0.2 MB
    int*   local    = (int*)ws;   ws += (size_t)(SCAN_BLOCKS * 256) * sizeof(int);
    int*   blocksum = (int*)ws;   ws += (size_t)SCAN_BLOCKS * sizeof(int);
    int*   base     = (int*)ws;   ws += (size_t)((SCAN_BLOCKS + 63) & ~63) * sizeof(int);
    int2*  csr      = (int2*)ws;  ws += (size_t)N_EDGES * sizeof(int2);          //  6.4 MB

    hipMemsetAsync(deg, 0, (size_t)N_NODES * sizeof(int), stream);

    node_phase<<<N_NODES / MB, 256, 0, stream>>>(
        x, W, att_src, att_dst, ei, deg, (unsigned short*)h, a_src, a_dst);

    scan_local<<<SCAN_BLOCKS, 256, 0, stream>>>(deg, local, blocksum);
    scan_base<<<1, 256, 0, stream>>>(blocksum, base);
    k_fill<<<(N_EDGES + 255) / 256, 256, 0, stream>>>(ei, edge_attr, local, base,
                                                      deg, csr);

    gather_node<<<N_NODES / 4, 256, 0, stream>>>(
        local, base, csr, a_src, a_dst, h, x, b, gamma, beta,
        att_edge, lin_w, lin_b, (float*)d_out);
}